// Round 24
// baseline (42.482 us; speedup 1.0000x reference)
//
#include <hip/hip_runtime.h>
#include <cstdint>
#include <cstddef>

// ContrastiveLoss: B=8192, D=256 fp32 inputs.
// loss = mean_b [ log( exp(2*pos_b) + sum_c exp(2*z_i[b].z_k[c]) ) - 2*pos_b ]
// R23: R22 + B register ring depth 6 (was 4): refill distance 6 steps
// (~410 cyc at MFMA-bound pace) >= worst-case L2 latency. Single-variable
// test of "B-refill latency coverage is the residual binder". Everything
// else identical to R22 (verified): R20 grid (row-fast), contiguous
// 32 B/lane fragment layout, 32x32 wave tile, A in regs, no LDS/barriers,
// exp2 epilogue, lane-reduce + atomics once per wave.

constexpr int   D_DIM = 256;
constexpr float INV_T = 2.0f;        // 1/T, T=0.5
constexpr float LOG2E = 1.44269504f;

constexpr int BM = 128;         // block rows
constexpr int NT = 16;          // col-tiles per block (each 32 cols)

typedef __attribute__((ext_vector_type(8)))  int   i32x8;
typedef __attribute__((ext_vector_type(16))) float f32x16;

// ---------------------------------------------------------------------------
// Kernel 1: per-16-row group: norms, pos_logit, rowsum init, PACKED e4m3 out.
// (unchanged — verified) CONTIGUOUS pack: frag f = (row>>5)*4 + (c>>2);
//   lane = (row&31) + 32*((c>>1)&1);  byte = f*2048 + lane*32 + (c&1)*16.
// z_i additionally scaled by LOG2E (so GEMM's scale-A=2.0 yields exp2 arg).
// ---------------------------------------------------------------------------
__global__ __launch_bounds__(256) void prep_kernel(
    const float* __restrict__ ei, const float* __restrict__ ej,
    const float* __restrict__ ek,
    unsigned char* __restrict__ zip, unsigned char* __restrict__ zkp,
    float* __restrict__ pos_logit, float* __restrict__ rowsum)
{
    const int t  = (int)threadIdx.x;
    const int rl = t >> 4;              // row within group (0..15)
    const int c  = t & 15;              // 16-elem chunk (0..15)
    const int g  = (int)blockIdx.x;     // 16-row group
    const int row = g * 16 + rl;

    const float4* pi = (const float4*)(ei + (size_t)row * D_DIM + c * 16);
    const float4* pj = (const float4*)(ej + (size_t)row * D_DIM + c * 16);
    const float4* pk = (const float4*)(ek + (size_t)row * D_DIM + c * 16);
    float4 vi[4], vj[4], vk[4];
    #pragma unroll
    for (int q = 0; q < 4; ++q) { vi[q] = pi[q]; vj[q] = pj[q]; vk[q] = pk[q]; }

    float ssi = 0.f, ssj = 0.f, ssk = 0.f, dij = 0.f;
    #pragma unroll
    for (int q = 0; q < 4; ++q) {
        ssi += vi[q].x*vi[q].x + vi[q].y*vi[q].y + vi[q].z*vi[q].z + vi[q].w*vi[q].w;
        ssj += vj[q].x*vj[q].x + vj[q].y*vj[q].y + vj[q].z*vj[q].z + vj[q].w*vj[q].w;
        ssk += vk[q].x*vk[q].x + vk[q].y*vk[q].y + vk[q].z*vk[q].z + vk[q].w*vk[q].w;
        dij += vi[q].x*vj[q].x + vi[q].y*vj[q].y + vi[q].z*vj[q].z + vi[q].w*vj[q].w;
    }
    #pragma unroll
    for (int off = 1; off <= 8; off <<= 1) {    // reduce over the 16 c-lanes
        ssi += __shfl_xor(ssi, off);
        ssj += __shfl_xor(ssj, off);
        ssk += __shfl_xor(ssk, off);
        dij += __shfl_xor(dij, off);
    }
    const float rn = 1.0f / fmaxf(sqrtf(ssi), 1e-12f);
    const float ri = rn * LOG2E;                          // fold log2(e)
    const float rj = 1.0f / fmaxf(sqrtf(ssj), 1e-12f);
    const float rk = 1.0f / fmaxf(sqrtf(ssk), 1e-12f);

    uint4 uiv, ukv;
    {
        unsigned int wi[4], wk[4];
        #pragma unroll
        for (int q = 0; q < 4; ++q) {
            const float* fi = &vi[q].x;
            const float* fk = &vk[q].x;
            int a = 0, b = 0;
            a = __builtin_amdgcn_cvt_pk_fp8_f32(fi[0] * ri, fi[1] * ri, a, false);
            a = __builtin_amdgcn_cvt_pk_fp8_f32(fi[2] * ri, fi[3] * ri, a, true);
            b = __builtin_amdgcn_cvt_pk_fp8_f32(fk[0] * rk, fk[1] * rk, b, false);
            b = __builtin_amdgcn_cvt_pk_fp8_f32(fk[2] * rk, fk[3] * rk, b, true);
            wi[q] = (unsigned int)a;
            wk[q] = (unsigned int)b;
        }
        uiv = make_uint4(wi[0], wi[1], wi[2], wi[3]);
        ukv = make_uint4(wk[0], wk[1], wk[2], wk[3]);
    }
    const int f    = (row >> 5) * 4 + (c >> 2);
    const int lane = (row & 31) + 32 * ((c >> 1) & 1);
    const size_t off = (size_t)f * 2048 + lane * 32 + (c & 1) * 16;
    *(uint4*)(zip + off) = uiv;
    *(uint4*)(zkp + off) = ukv;

    if (c == 0) {
        pos_logit[row] = dij * rn * rj * INV_T;   // plain 2*(zi.zj), no log2e
        rowsum[row]    = 0.0f;
    }
}

// ---------------------------------------------------------------------------
// Kernel 2: rows [bR*128,+128) x cols [bC*512,+512) of exp2-sum of
// 2*log2e*(z_i . z_k); bR = blockIdx.x (FAST), bC = blockIdx.y.
// 4 waves = row slices; wave tile 32x32; 64 steps fully unrolled.
// A: 4 frags in registers (loaded once). B: ring depth 6 (s % 6 slots,
// compile-time). No LDS, no barriers.
// ---------------------------------------------------------------------------
__global__ __launch_bounds__(256) void sim_mfma_kernel(
    const unsigned char* __restrict__ zip, const unsigned char* __restrict__ zkp,
    float* __restrict__ rowsum)
{
    const int t  = (int)threadIdx.x;
    const int w  = t >> 6;        // wave 0..3 = row slice
    const int l  = t & 63;
    const int bR = (int)blockIdx.x;    // row block (fast)
    const int bC = (int)blockIdx.y;    // col block
    const int rowBase = bR * BM;

    // ---- A frags -> registers (once): global frag (bR*4+w)*4 + kt.
    const unsigned char* Abase =
        zip + ((size_t)(bR * 4 + w) * 4) * 2048 + (size_t)l * 32;
    i32x8 a0 = *(const i32x8*)(Abase);
    i32x8 a1 = *(const i32x8*)(Abase + 2048);
    i32x8 a2 = *(const i32x8*)(Abase + 4096);
    i32x8 a3 = *(const i32x8*)(Abase + 6144);

    // ---- B frag: frag s (= nt*4+kt) at Bbase + s*2048 (contiguous 32B/lane)
    const unsigned char* Bbase =
        zkp + ((size_t)bC * 16 * 4) * 2048 + (size_t)l * 32;

    // ---- B ring, depth 6 (static names; slot = s % 6, compile-time) ----
    i32x8 b0 = *(const i32x8*)(Bbase);
    i32x8 b1 = *(const i32x8*)(Bbase + 2048);
    i32x8 b2 = *(const i32x8*)(Bbase + 4096);
    i32x8 b3 = *(const i32x8*)(Bbase + 6144);
    i32x8 b4 = *(const i32x8*)(Bbase + 8192);
    i32x8 b5 = *(const i32x8*)(Bbase + 10240);

    float partAcc[16] = {};

    #pragma unroll
    for (int nt = 0; nt < NT; ++nt) {
        f32x16 acc = {};

        #pragma unroll
        for (int k4 = 0; k4 < 4; ++k4) {
            const int s  = nt * 4 + k4;           // compile-time
            const int s6 = (s + 6 > NT * 4 - 1) ? (NT * 4 - 1) : (s + 6);
            const int sl = s % 6;                 // compile-time slot

            __builtin_amdgcn_s_setprio(1);
            acc = __builtin_amdgcn_mfma_scale_f32_32x32x64_f8f6f4(
                (k4 == 0) ? a0 : (k4 == 1) ? a1 : (k4 == 2) ? a2 : a3,
                (sl == 0) ? b0 : (sl == 1) ? b1 : (sl == 2) ? b2
                          : (sl == 3) ? b3 : (sl == 4) ? b4 : b5,
                acc,
                0, 0,                 // cbsz=fp8(A), blgp=fp8(B)
                0, 0x00000080,        // scale A = 2.0 (1/T)
                0, 0x0000007F);       // scale B = 1.0
            __builtin_amdgcn_s_setprio(0);

            // refill this slot for step s+6 (distance 6)
            if (sl == 0)      { b0 = *(const i32x8*)(Bbase + (size_t)s6 * 2048); }
            else if (sl == 1) { b1 = *(const i32x8*)(Bbase + (size_t)s6 * 2048); }
            else if (sl == 2) { b2 = *(const i32x8*)(Bbase + (size_t)s6 * 2048); }
            else if (sl == 3) { b3 = *(const i32x8*)(Bbase + (size_t)s6 * 2048); }
            else if (sl == 4) { b4 = *(const i32x8*)(Bbase + (size_t)s6 * 2048); }
            else              { b5 = *(const i32x8*)(Bbase + (size_t)s6 * 2048); }
        }

        // per-tile epilogue: bare exp2 + in-lane partial sums
        #pragma unroll
        for (int r = 0; r < 16; ++r)
            partAcc[r] += exp2f(acc[r]);
    }

    // wave epilogue: reduce across the 32 column-lanes (xor<32 stays in half)
    #pragma unroll
    for (int off = 1; off <= 16; off <<= 1)
        #pragma unroll
        for (int r = 0; r < 16; ++r)
            partAcc[r] += __shfl_xor(partAcc[r], off);

    if ((l & 31) == 0) {
        const int hi = l >> 5;           // C/D: row = (r&3) + 8*(r>>2) + 4*hi
        #pragma unroll
        for (int r = 0; r < 16; ++r) {
            const int rr = (r & 3) + 8 * (r >> 2) + 4 * hi;
            atomicAdd(&rowsum[rowBase + w * 32 + rr], partAcc[r]);
        }
    }
}

// ---------------------------------------------------------------------------
// Kernel 3: loss = mean_b [ log(exp(pos_b) + rowsum_b) - pos_b ]
// ---------------------------------------------------------------------------
__global__ __launch_bounds__(1024) void finalize_kernel(
    const float* __restrict__ pos_logit, const float* __restrict__ rowsum,
    float* __restrict__ out, int B)
{
    __shared__ float red[1024];
    float acc = 0.f;
    for (int b = (int)threadIdx.x; b < B; b += 1024) {
        const float pl = pos_logit[b];
        acc += logf(expf(pl) + rowsum[b]) - pl;
    }
    red[threadIdx.x] = acc;
    __syncthreads();
    #pragma unroll
    for (int s = 512; s; s >>= 1) {
        if ((int)threadIdx.x < s) red[threadIdx.x] += red[threadIdx.x + s];
        __syncthreads();
    }
    if (threadIdx.x == 0) out[0] = red[0] / (float)B;
}

// ---------------------------------------------------------------------------
extern "C" void kernel_launch(void* const* d_in, const int* in_sizes, int n_in,
                              void* d_out, int out_size, void* d_ws, size_t ws_size,
                              hipStream_t stream)
{
    const float* ei = (const float*)d_in[0];
    const float* ej = (const float*)d_in[1];
    const float* ek = (const float*)d_in[2];
    const int B = in_sizes[0] / D_DIM;   // 8192

    unsigned char* zip = (unsigned char*)d_ws;              // 2 MB packed fp8
    unsigned char* zkp = zip + (size_t)B * D_DIM;           // 2 MB packed fp8
    float* rowsum      = (float*)(zkp + (size_t)B * D_DIM);
    float* pos_logit   = rowsum + B;

    prep_kernel<<<dim3(B / 16), dim3(256), 0, stream>>>(
        ei, ej, ek, zip, zkp, pos_logit, rowsum);

    // grid: x = ROW blocks (fast -> each XCD L2 holds one B panel at a time),
    //       y = COL blocks
    dim3 grid(B / BM, B / (NT * 32));    // (64, 16) = 1024 blocks
    sim_mfma_kernel<<<grid, dim3(256), 0, stream>>>(zip, zkp, rowsum);

    finalize_kernel<<<dim3(1), dim3(1024), 0, stream>>>(
        pos_logit, rowsum, (float*)d_out, B);
}

// Round 25
// 41.068 us; speedup vs baseline: 1.0344x; 1.0344x over previous
//
#include <hip/hip_runtime.h>
#include <cstdint>
#include <cstddef>

// ContrastiveLoss: B=8192, D=256 fp32 inputs.
// loss = mean_b [ log( exp(2*pos_b) + sum_c exp(2*z_i[b].z_k[c]) ) - 2*pos_b ]
// R24: sim unchanged (R22 verified: fp8-MX 32x32 wave tile, A in regs,
// B ring depth 4, contiguous 32B/lane frags, row-fast grid, no LDS/barriers).
// prep v2: 32 threads/row (16 waves/CU, 2x TLP for the HBM-bound pass).
// finalize two-stage: 32-block partial reduce + 1-wave final sum.

constexpr int   D_DIM = 256;
constexpr float INV_T = 2.0f;        // 1/T, T=0.5
constexpr float LOG2E = 1.44269504f;

constexpr int BM = 128;         // block rows
constexpr int NT = 16;          // col-tiles per block (each 32 cols)

typedef __attribute__((ext_vector_type(8)))  int   i32x8;
typedef __attribute__((ext_vector_type(16))) float f32x16;

// ---------------------------------------------------------------------------
// Kernel 1 (v2): 8 rows/block, 32 threads/row (each 8 elems).
// Pack (contiguous, R22-verified): for 16-elem chunk c: f = (row>>5)*4+(c>>2),
// lane = (row&31)+32*((c>>1)&1), byte = f*2048 + lane*32 + (c&1)*16.
// Here c8 = t&31 (8-elem chunk): c = c8>>1, extra +8*(c8&1) within the 16B.
// z_i scaled by LOG2E (GEMM scale-A=2.0 then yields exp2 argument).
// ---------------------------------------------------------------------------
__global__ __launch_bounds__(256) void prep_kernel(
    const float* __restrict__ ei, const float* __restrict__ ej,
    const float* __restrict__ ek,
    unsigned char* __restrict__ zip, unsigned char* __restrict__ zkp,
    float* __restrict__ pos_logit, float* __restrict__ rowsum)
{
    const int t   = (int)threadIdx.x;
    const int rl  = t >> 5;             // row within block (0..7)
    const int c8  = t & 31;             // 8-elem chunk (0..31)
    const int row = (int)blockIdx.x * 8 + rl;

    const float4* pi = (const float4*)(ei + (size_t)row * D_DIM + c8 * 8);
    const float4* pj = (const float4*)(ej + (size_t)row * D_DIM + c8 * 8);
    const float4* pk = (const float4*)(ek + (size_t)row * D_DIM + c8 * 8);
    float4 vi[2], vj[2], vk[2];
    #pragma unroll
    for (int q = 0; q < 2; ++q) { vi[q] = pi[q]; vj[q] = pj[q]; vk[q] = pk[q]; }

    float ssi = 0.f, ssj = 0.f, ssk = 0.f, dij = 0.f;
    #pragma unroll
    for (int q = 0; q < 2; ++q) {
        ssi += vi[q].x*vi[q].x + vi[q].y*vi[q].y + vi[q].z*vi[q].z + vi[q].w*vi[q].w;
        ssj += vj[q].x*vj[q].x + vj[q].y*vj[q].y + vj[q].z*vj[q].z + vj[q].w*vj[q].w;
        ssk += vk[q].x*vk[q].x + vk[q].y*vk[q].y + vk[q].z*vk[q].z + vk[q].w*vk[q].w;
        dij += vi[q].x*vj[q].x + vi[q].y*vj[q].y + vi[q].z*vj[q].z + vi[q].w*vj[q].w;
    }
    #pragma unroll
    for (int off = 1; off <= 16; off <<= 1) {   // reduce over the 32 c8-lanes
        ssi += __shfl_xor(ssi, off);
        ssj += __shfl_xor(ssj, off);
        ssk += __shfl_xor(ssk, off);
        dij += __shfl_xor(dij, off);
    }
    const float rn = 1.0f / fmaxf(sqrtf(ssi), 1e-12f);
    const float ri = rn * LOG2E;                          // fold log2(e)
    const float rj = 1.0f / fmaxf(sqrtf(ssj), 1e-12f);
    const float rk = 1.0f / fmaxf(sqrtf(ssk), 1e-12f);

    // 8 values each -> 2 u32 of fp8 (cvt_pk lo/hi)
    uint2 uiv, ukv;
    {
        unsigned int wi[2], wk[2];
        #pragma unroll
        for (int q = 0; q < 2; ++q) {
            const float* fi = &vi[q].x;
            const float* fk = &vk[q].x;
            int a = 0, b = 0;
            a = __builtin_amdgcn_cvt_pk_fp8_f32(fi[0] * ri, fi[1] * ri, a, false);
            a = __builtin_amdgcn_cvt_pk_fp8_f32(fi[2] * ri, fi[3] * ri, a, true);
            b = __builtin_amdgcn_cvt_pk_fp8_f32(fk[0] * rk, fk[1] * rk, b, false);
            b = __builtin_amdgcn_cvt_pk_fp8_f32(fk[2] * rk, fk[3] * rk, b, true);
            wi[q] = (unsigned int)a;
            wk[q] = (unsigned int)b;
        }
        uiv = make_uint2(wi[0], wi[1]);
        ukv = make_uint2(wk[0], wk[1]);
    }
    const int f    = (row >> 5) * 4 + (c8 >> 3);
    const int lane = (row & 31) + 32 * ((c8 >> 2) & 1);
    const size_t off = (size_t)f * 2048 + lane * 32
                     + ((c8 >> 1) & 1) * 16 + (c8 & 1) * 8;
    *(uint2*)(zip + off) = uiv;
    *(uint2*)(zkp + off) = ukv;

    if (c8 == 0) {
        pos_logit[row] = dij * rn * rj * INV_T;   // plain 2*(zi.zj), no log2e
        rowsum[row]    = 0.0f;
    }
}

// ---------------------------------------------------------------------------
// Kernel 2 (unchanged R22): rows [bR*128,+128) x cols [bC*512,+512).
// bR = blockIdx.x (FAST), bC = blockIdx.y. 4 waves = row slices; wave tile
// 32x32; 64 steps fully unrolled. A in regs; B ring depth 4. No LDS/barriers.
// ---------------------------------------------------------------------------
__global__ __launch_bounds__(256) void sim_mfma_kernel(
    const unsigned char* __restrict__ zip, const unsigned char* __restrict__ zkp,
    float* __restrict__ rowsum)
{
    const int t  = (int)threadIdx.x;
    const int w  = t >> 6;        // wave 0..3 = row slice
    const int l  = t & 63;
    const int bR = (int)blockIdx.x;    // row block (fast)
    const int bC = (int)blockIdx.y;    // col block
    const int rowBase = bR * BM;

    const unsigned char* Abase =
        zip + ((size_t)(bR * 4 + w) * 4) * 2048 + (size_t)l * 32;
    i32x8 a0 = *(const i32x8*)(Abase);
    i32x8 a1 = *(const i32x8*)(Abase + 2048);
    i32x8 a2 = *(const i32x8*)(Abase + 4096);
    i32x8 a3 = *(const i32x8*)(Abase + 6144);

    const unsigned char* Bbase =
        zkp + ((size_t)bC * 16 * 4) * 2048 + (size_t)l * 32;

    i32x8 b0 = *(const i32x8*)(Bbase);
    i32x8 b1 = *(const i32x8*)(Bbase + 2048);
    i32x8 b2 = *(const i32x8*)(Bbase + 4096);
    i32x8 b3 = *(const i32x8*)(Bbase + 6144);

    float partAcc[16] = {};

    #pragma unroll
    for (int nt = 0; nt < NT; ++nt) {
        f32x16 acc = {};

        #pragma unroll
        for (int k4 = 0; k4 < 4; ++k4) {
            const int s  = nt * 4 + k4;           // compile-time
            const int s4 = (s + 4 > NT * 4 - 1) ? (NT * 4 - 1) : (s + 4);

            __builtin_amdgcn_s_setprio(1);
            acc = __builtin_amdgcn_mfma_scale_f32_32x32x64_f8f6f4(
                (k4 == 0) ? a0 : (k4 == 1) ? a1 : (k4 == 2) ? a2 : a3,
                (s % 4 == 0) ? b0 : (s % 4 == 1) ? b1
                             : (s % 4 == 2) ? b2 : b3,
                acc,
                0, 0,                 // cbsz=fp8(A), blgp=fp8(B)
                0, 0x00000080,        // scale A = 2.0 (1/T)
                0, 0x0000007F);       // scale B = 1.0
            __builtin_amdgcn_s_setprio(0);

            if (s % 4 == 0)      { b0 = *(const i32x8*)(Bbase + (size_t)s4 * 2048); }
            else if (s % 4 == 1) { b1 = *(const i32x8*)(Bbase + (size_t)s4 * 2048); }
            else if (s % 4 == 2) { b2 = *(const i32x8*)(Bbase + (size_t)s4 * 2048); }
            else                 { b3 = *(const i32x8*)(Bbase + (size_t)s4 * 2048); }
        }

        #pragma unroll
        for (int r = 0; r < 16; ++r)
            partAcc[r] += exp2f(acc[r]);
    }

    #pragma unroll
    for (int off = 1; off <= 16; off <<= 1)
        #pragma unroll
        for (int r = 0; r < 16; ++r)
            partAcc[r] += __shfl_xor(partAcc[r], off);

    if ((l & 31) == 0) {
        const int hi = l >> 5;           // C/D: row = (r&3) + 8*(r>>2) + 4*hi
        #pragma unroll
        for (int r = 0; r < 16; ++r) {
            const int rr = (r & 3) + 8 * (r >> 2) + 4 * hi;
            atomicAdd(&rowsum[rowBase + w * 32 + rr], partAcc[r]);
        }
    }
}

// ---------------------------------------------------------------------------
// Kernel 3a: stage-1 reduce — 32 blocks x 256 threads, one row per thread.
// partial[blockIdx] = sum over 256 rows of [ log(exp(pl)+rs) - pl ].
// ---------------------------------------------------------------------------
__global__ __launch_bounds__(256) void finalize1_kernel(
    const float* __restrict__ pos_logit, const float* __restrict__ rowsum,
    float* __restrict__ partial)
{
    __shared__ float red[256];
    const int b = (int)blockIdx.x * 256 + (int)threadIdx.x;
    const float pl = pos_logit[b];
    red[threadIdx.x] = logf(expf(pl) + rowsum[b]) - pl;
    __syncthreads();
    #pragma unroll
    for (int s = 128; s; s >>= 1) {
        if ((int)threadIdx.x < s) red[threadIdx.x] += red[threadIdx.x + s];
        __syncthreads();
    }
    if (threadIdx.x == 0) partial[blockIdx.x] = red[0];
}

// ---------------------------------------------------------------------------
// Kernel 3b: stage-2 — one wave sums 32 partials, writes mean.
// ---------------------------------------------------------------------------
__global__ __launch_bounds__(64) void finalize2_kernel(
    const float* __restrict__ partial, float* __restrict__ out, int B)
{
    const int l = (int)threadIdx.x;
    float v = (l < 32) ? partial[l] : 0.0f;
    #pragma unroll
    for (int off = 1; off <= 16; off <<= 1)
        v += __shfl_xor(v, off);
    if (l == 0) out[0] = v / (float)B;
}

// ---------------------------------------------------------------------------
extern "C" void kernel_launch(void* const* d_in, const int* in_sizes, int n_in,
                              void* d_out, int out_size, void* d_ws, size_t ws_size,
                              hipStream_t stream)
{
    const float* ei = (const float*)d_in[0];
    const float* ej = (const float*)d_in[1];
    const float* ek = (const float*)d_in[2];
    const int B = in_sizes[0] / D_DIM;   // 8192

    unsigned char* zip = (unsigned char*)d_ws;              // 2 MB packed fp8
    unsigned char* zkp = zip + (size_t)B * D_DIM;           // 2 MB packed fp8
    float* rowsum      = (float*)(zkp + (size_t)B * D_DIM);
    float* pos_logit   = rowsum + B;
    float* partial     = pos_logit + B;                     // 32 floats

    prep_kernel<<<dim3(B / 8), dim3(256), 0, stream>>>(
        ei, ej, ek, zip, zkp, pos_logit, rowsum);

    // grid: x = ROW blocks (fast -> each XCD L2 holds one B panel at a time)
    dim3 grid(B / BM, B / (NT * 32));    // (64, 16) = 1024 blocks
    sim_mfma_kernel<<<grid, dim3(256), 0, stream>>>(zip, zkp, rowsum);

    finalize1_kernel<<<dim3(B / 256), dim3(256), 0, stream>>>(
        pos_logit, rowsum, partial);
    finalize2_kernel<<<dim3(1), dim3(64), 0, stream>>>(
        partial, (float*)d_out, B);
}